// Round 15
// baseline (229.425 us; speedup 1.0000x reference)
//
#include <hip/hip_runtime.h>

#define D 64
#define BM 128        // queries per block
#define NCHUNK 8      // K split across blocks
#define NLIST (2 * NCHUNK)   // one winner list per (chunk, wn-wave)
#define DECAYF 0.8f
#define OMDF 0.2f
#define EPSF 1e-5f
#define INVS 4.8828125e-4f   // 2^-11

typedef _Float16 f16;
typedef _Float16 f16x8 __attribute__((ext_vector_type(8)));
typedef float f32x4 __attribute__((ext_vector_type(4)));

// non-temporal float4 load via native vector type (builtin rejects HIP_vector_type)
__device__ inline f32x4 ntload4(const float* p) {
    return __builtin_nontemporal_load(reinterpret_cast<const f32x4*>(p));
}

// ---------- prep: frag-major f16 hi/lo split + e2 (LDS reduce) + sum(cluster_size) ----
__global__ __launch_bounds__(512) void prep_kernel(
    const float* __restrict__ emb, const float* __restrict__ cluster_size,
    f16* __restrict__ eh2, f16* __restrict__ el2, float* __restrict__ e2,
    float* __restrict__ cs_sum, int K)
{
    __shared__ float red[512];
    int t = blockIdx.x * 512 + threadIdx.x;
    int lane = t & 63;
    int sub  = (t >> 6) & 7;
    int tile = t >> 9;
    int wn = sub >> 2, nf = (sub >> 1) & 1, ks = sub & 1;
    int lrow = lane & 15, lkg = lane >> 4;
    int k  = tile * 64 + wn * 32 + nf * 16 + lrow;
    int d0 = ks * 32 + lkg * 8;

    const float4* p = reinterpret_cast<const float4*>(emb + (size_t)k * D + d0);
    float4 a = p[0], b = p[1];
    float v[8] = {a.x, a.y, a.z, a.w, b.x, b.y, b.z, b.w};
    union { f16 h[8]; uint4 u; } H, L;
    float part = 0.f;
#pragma unroll
    for (int j = 0; j < 8; ++j) {
        part = fmaf(v[j], v[j], part);
        f16 h = (f16)v[j];
        H.h[j] = h;
        L.h[j] = (f16)((v[j] - (float)h) * 2048.0f);
    }
    reinterpret_cast<uint4*>(eh2)[t] = H.u;
    reinterpret_cast<uint4*>(el2)[t] = L.u;

    red[threadIdx.x] = part;

    if (blockIdx.x < (K >> 9)) {
        float cv = cluster_size[t];
#pragma unroll
        for (int m = 1; m < 64; m <<= 1) cv += __shfl_xor(cv, m, 64);
        if ((threadIdx.x & 63) == 0) atomicAdd(cs_sum, cv);
    }
    __syncthreads();

    if (threadIdx.x < 64) {
        int r = threadIdx.x;
        int rwn = r >> 5, rnf = (r >> 4) & 1, rlr = r & 15;
        float s = 0.f;
#pragma unroll
        for (int kks = 0; kks < 2; ++kks)
#pragma unroll
            for (int g = 0; g < 4; ++g)
                s += red[((rwn * 2 + rnf) * 2 + kks) * 64 + g * 16 + rlr];
        e2[tile * 64 + r] = s;
    }
}

// ---------- MFMA 3-pass split-f16: depth-2 prefetch (3 buffers) + nt x-loads ----------
__global__ __launch_bounds__(256, 2) void argmin_kernel(
    const float* __restrict__ x, const f16* __restrict__ eh2, const f16* __restrict__ el2,
    const float* __restrict__ e2, int* __restrict__ pidx, int n, int K)
{
    __shared__ float se2a[1024];     // whole-chunk +0.5*e2 (4KB)

    const int tx   = threadIdx.x;
    const int lane = tx & 63;
    const int wid  = tx >> 6;
    const int wm   = wid >> 1, wn = wid & 1;
    const int lrow = lane & 15;
    const int lkg  = lane >> 4;

    const int chunk = blockIdx.x % NCHUNK;
    const int mblk  = blockIdx.x / NCHUNK;
    const int q0    = mblk * BM;
    const int kc    = K / NCHUNK;    // 1024
    const int k0    = chunk * kc;
    const int gt0   = chunk * (kc / 64);
    const int NT    = kc / 64;       // 16 tiles of 64 codes (NT % 3 == 1)

    // ---- A fragments (NEGATED, non-temporal x): f16 hi/lo + 0.5*f2 per slot ----
    f16x8 ah[4][2], al[4][2];
    f32x4 hf2[4];
#pragma unroll
    for (int m = 0; m < 4; ++m) {
        float f2part = 0.f;
#pragma unroll
        for (int ks = 0; ks < 2; ++ks) {
            int row = q0 + wm * 64 + m * 16 + lrow;
            const float* p = x + (size_t)row * D + ks * 32 + lkg * 8;
            f32x4 va = ntload4(p), vb = ntload4(p + 4);   // nt: don't evict B-stream
            float t[8] = {va[0], va[1], va[2], va[3], vb[0], vb[1], vb[2], vb[3]};
#pragma unroll
            for (int j = 0; j < 8; ++j) {
                f2part = fmaf(t[j], t[j], f2part);
                float nt = -t[j];
                f16 h = (f16)nt;
                ah[m][ks][j] = h;
                al[m][ks][j] = (f16)((nt - (float)h) * 2048.0f);
            }
        }
        f2part += __shfl_xor(f2part, 16, 64);
        f2part += __shfl_xor(f2part, 32, 64);
#pragma unroll
        for (int r = 0; r < 4; ++r)
            hf2[m][r] = 0.5f * __shfl(f2part, lkg * 4 + r, 64);
    }

    // ---- whole-chunk e2 table, prescaled by +0.5 ----
    for (int i = tx; i < kc; i += 256) se2a[i] = 0.5f * e2[k0 + i];
    __syncthreads();   // the ONLY barrier

    // ---- packed top-1 (MINIMIZE uint(t')|tag) per C-slot ----
    unsigned int pbest[16];
#pragma unroll
    for (int s = 0; s < 16; ++s) pbest[s] = 0xFFFFFFFFu;

    auto LOADB = [&](f16x8 (&BH)[2][2], f16x8 (&BL)[2][2], int ttv) {
        const f16* bhb = eh2 + ((size_t)(gt0 + ttv) << 12);
        const f16* blb = el2 + ((size_t)(gt0 + ttv) << 12);
#pragma unroll
        for (int nf = 0; nf < 2; ++nf)
#pragma unroll
            for (int ks = 0; ks < 2; ++ks) {
                int sub = (wn * 2 + nf) * 2 + ks;
                BH[nf][ks] = *reinterpret_cast<const f16x8*>(bhb + sub * 512 + lane * 8);
                BL[nf][ks] = *reinterpret_cast<const f16x8*>(blb + sub * 512 + lane * 8);
            }
    };

    auto COMPUTE = [&](const f16x8 (&BH)[2][2], const f16x8 (&BL)[2][2], int ttv) {
        const float he0 = se2a[ttv * 64 + wn * 32 + lrow];
        const float he1 = se2a[ttv * 64 + wn * 32 + 16 + lrow];
        const unsigned int tagA = (unsigned int)(ttv * 2);
        const unsigned int tagB = tagA + 1u;
#pragma unroll
        for (int m = 0; m < 4; ++m) {
            f32x4 hh0 = hf2[m] + he0;
            f32x4 hh1 = hf2[m] + he1;
            f32x4 md0 = {0.f, 0.f, 0.f, 0.f};
            f32x4 md1 = {0.f, 0.f, 0.f, 0.f};
            __builtin_amdgcn_s_setprio(1);
            hh0 = __builtin_amdgcn_mfma_f32_16x16x32_f16(ah[m][0], BH[0][0], hh0, 0, 0, 0);
            hh1 = __builtin_amdgcn_mfma_f32_16x16x32_f16(ah[m][0], BH[1][0], hh1, 0, 0, 0);
            hh0 = __builtin_amdgcn_mfma_f32_16x16x32_f16(ah[m][1], BH[0][1], hh0, 0, 0, 0);
            hh1 = __builtin_amdgcn_mfma_f32_16x16x32_f16(ah[m][1], BH[1][1], hh1, 0, 0, 0);
            md0 = __builtin_amdgcn_mfma_f32_16x16x32_f16(al[m][0], BH[0][0], md0, 0, 0, 0);
            md1 = __builtin_amdgcn_mfma_f32_16x16x32_f16(al[m][0], BH[1][0], md1, 0, 0, 0);
            md0 = __builtin_amdgcn_mfma_f32_16x16x32_f16(al[m][1], BH[0][1], md0, 0, 0, 0);
            md1 = __builtin_amdgcn_mfma_f32_16x16x32_f16(al[m][1], BH[1][1], md1, 0, 0, 0);
            md0 = __builtin_amdgcn_mfma_f32_16x16x32_f16(ah[m][0], BL[0][0], md0, 0, 0, 0);
            md1 = __builtin_amdgcn_mfma_f32_16x16x32_f16(ah[m][0], BL[1][0], md1, 0, 0, 0);
            md0 = __builtin_amdgcn_mfma_f32_16x16x32_f16(ah[m][1], BL[0][1], md0, 0, 0, 0);
            md1 = __builtin_amdgcn_mfma_f32_16x16x32_f16(ah[m][1], BL[1][1], md1, 0, 0, 0);
            __builtin_amdgcn_s_setprio(0);
#pragma unroll
            for (int r = 0; r < 4; ++r) {
                float tA = fmaf(md0[r], INVS, hh0[r]);   // 0.5*d2, >= 0
                float tB = fmaf(md1[r], INVS, hh1[r]);
                unsigned int uA = (__float_as_uint(tA) & 0xFFFFFFE0u) | tagA;
                unsigned int uB = (__float_as_uint(tB) & 0xFFFFFFE0u) | tagB;
                unsigned int w = uA < uB ? uA : uB;
                int s = m * 4 + r;
                pbest[s] = pbest[s] < w ? pbest[s] : w;
            }
        }
    };

    // ---- 3-buffer register pipeline, prefetch depth 2 (tile t uses buffer t%3) ----
    f16x8 h0[2][2], l0[2][2], h1[2][2], l1[2][2], h2[2][2], l2[2][2];
    LOADB(h0, l0, 0);
    LOADB(h1, l1, 1);
#pragma unroll 1
    for (int tt = 0; tt < NT - 1; tt += 3) {
        LOADB(h2, l2, tt + 2);                    // tt+2 <= NT-2: always valid
        COMPUTE(h0, l0, tt);
        LOADB(h0, l0, tt + 3);                    // tt+3 <= NT-1: always valid
        COMPUTE(h1, l1, tt + 1);
        if (tt + 4 < NT) LOADB(h1, l1, tt + 4);
        COMPUTE(h2, l2, tt + 2);
    }
    COMPUTE(h0, l0, NT - 1);                      // NT%3==1: tail tile uses buffer 0

    // ---- merge across the 16 col-lanes (min packed; tie -> lower code id) ----
#pragma unroll
    for (int s = 0; s < 16; ++s) {
        unsigned int u = pbest[s];
        unsigned int tag = u & 31u;
        int cid = (int)((tag >> 1) << 6) | (int)((tag & 1u) << 4) | (wn << 5) | lrow;
#pragma unroll
        for (int xm = 1; xm < 16; xm <<= 1) {
            unsigned int ou = __shfl_xor(u, xm, 64);
            int          oc = __shfl_xor(cid, xm, 64);
            if (ou < u || (ou == u && oc < cid)) { u = ou; cid = oc; }
        }
        if (lrow == 0) {
            int m = s >> 2, r = s & 3;
            int row = q0 + wm * 64 + m * 16 + lkg * 4 + r;
            pidx[(size_t)(chunk * 2 + wn) * n + row] = k0 + cid;
        }
    }
}

// ---------- fused exact re-rank + quantize + scatter: wave/query, 4 lanes/candidate ----
__global__ __launch_bounds__(256) void rerank_kernel(
    const float* __restrict__ x, const float* __restrict__ emb, const float* __restrict__ e2,
    const int* __restrict__ pidx, float* __restrict__ out_ind, float* __restrict__ quant,
    float* __restrict__ embed_sum, float* __restrict__ counts, int n)
{
    int gid  = blockIdx.x * blockDim.x + threadIdx.x;
    int q    = gid >> 6;
    int lane = gid & 63;
    int c    = lane >> 2;
    int j    = lane & 3;
    if (q >= n) return;

    int k = pidx[(size_t)c * n + q];
    const float4* ep = reinterpret_cast<const float4*>(emb + (size_t)k * D);
    const float4* xp = reinterpret_cast<const float4*>(x + (size_t)q * D);

    float a0 = 0.f, a1 = 0.f, a2 = 0.f, a3 = 0.f;
#pragma unroll
    for (int i = 0; i < 4; ++i) {
        float4 e4 = ep[j + 4 * i];
        float4 x4 = xp[j + 4 * i];
        a0 = fmaf(x4.x, e4.x, a0);
        a1 = fmaf(x4.y, e4.y, a1);
        a2 = fmaf(x4.z, e4.z, a2);
        a3 = fmaf(x4.w, e4.w, a3);
    }
    float p = (a0 + a1) + (a2 + a3);
    p += __shfl_xor(p, 1, 64);
    p += __shfl_xor(p, 2, 64);
    float dist = fmaf(p, -2.0f, e2[k]);
    int   bk   = k;

#pragma unroll
    for (int xm = 4; xm < 64; xm <<= 1) {
        float od = __shfl_xor(dist, xm, 64);
        int   ok = __shfl_xor(bk, xm, 64);
        if (od < dist || (od == dist && ok < bk)) { dist = od; bk = ok; }
    }

    float xv = x[(size_t)q * D + lane];
    quant[(size_t)q * D + lane] = emb[(size_t)bk * D + lane];
    atomicAdd(embed_sum + (size_t)bk * D + lane, xv);
    if (lane == 0) {
        out_ind[q] = (float)bk;
        atomicAdd(counts + bk, 1.0f);
    }
}

// ---------- single fused EMA: cluster_size + embed_avg + normalize ----------
__global__ __launch_bounds__(256) void ema_kernel(
    const float* __restrict__ cluster_size, const float* __restrict__ embed_avg,
    const float* __restrict__ cs_sum, float* __restrict__ ncs,
    float* __restrict__ nea, float* __restrict__ enorm, int K, int n)
{
    int gid = blockIdx.x * blockDim.x + threadIdx.x;
    if (gid >= K * D) return;
    int k = gid >> 6;
    float total = DECAYF * cs_sum[0] + OMDF * (float)n;
    float cnew  = cluster_size[k] * DECAYF + ncs[k] * OMDF;
    if ((gid & 63) == 0) ncs[k] = cnew;
    float v = embed_avg[gid] * DECAYF + nea[gid] * OMDF;
    nea[gid] = v;
    float smoothed = (cnew + EPSF) / (total + (float)K * EPSF) * total;
    enorm[gid] = v / smoothed;
}

extern "C" void kernel_launch(void* const* d_in, const int* in_sizes, int n_in,
                              void* d_out, int out_size, void* d_ws, size_t ws_size,
                              hipStream_t stream) {
    const float* x            = (const float*)d_in[0];   // [n, 64]
    const float* emb          = (const float*)d_in[1];   // [K, 64]
    const float* cluster_size = (const float*)d_in[2];   // [K]
    const float* embed_avg    = (const float*)d_in[3];   // [K, 64]

    const int n = in_sizes[0] / D;   // 16384
    const int K = in_sizes[1] / D;   // 8192

    // output layout (fp32): quantize | embed_ind | embed_normalized | new_cluster_size | new_embed_avg
    float* out     = (float*)d_out;
    float* quant   = out;                        // n*D
    float* out_ind = quant + (size_t)n * D;      // n
    float* enorm   = out_ind + n;                // K*D  (scratch for eh2/el2 until ema)
    float* ncs     = enorm + (size_t)K * D;      // K    (counts, then EMA'd in place)
    float* nea     = ncs + K;                    // K*D  (embed_sum, then EMA'd in place)

    f16* eh2 = reinterpret_cast<f16*>(enorm);    // K*D f16, fragment-major
    f16* el2 = eh2 + (size_t)K * D;              // K*D f16, fragment-major

    // workspace: e2 | pidx[NLIST][n] | cs_sum
    float* e2     = (float*)d_ws;                        // K
    int*   pidx   = (int*)(e2 + K);                      // NLIST*n
    float* cs_sum = (float*)(pidx + (size_t)NLIST * n);  // 1

    hipMemsetAsync(ncs, 0, (size_t)K * sizeof(float), stream);
    hipMemsetAsync(nea, 0, (size_t)K * D * sizeof(float), stream);
    hipMemsetAsync(cs_sum, 0, sizeof(float), stream);

    prep_kernel<<<K * 8 / 512, 512, 0, stream>>>(emb, cluster_size, eh2, el2, e2, cs_sum, K);
    argmin_kernel<<<(n / BM) * NCHUNK, 256, 0, stream>>>(x, eh2, el2, e2, pidx, n, K);
    rerank_kernel<<<(n * 64 + 255) / 256, 256, 0, stream>>>(
        x, emb, e2, pidx, out_ind, quant, nea, ncs, n);
    ema_kernel<<<(K * D + 255) / 256, 256, 0, stream>>>(
        cluster_size, embed_avg, cs_sum, ncs, nea, enorm, K, n);
}

// Round 16
// 97.239 us; speedup vs baseline: 2.3594x; 2.3594x over previous
//
#include <hip/hip_runtime.h>

#define D 64
#define BM 128        // queries per block
#define NCHUNK 8      // K split across blocks
#define NLIST (2 * NCHUNK)   // one winner list per (chunk, wn-wave)
#define DECAYF 0.8f
#define OMDF 0.2f
#define EPSF 1e-5f
#define INVS 4.8828125e-4f   // 2^-11

typedef _Float16 f16;
typedef _Float16 f16x8 __attribute__((ext_vector_type(8)));
typedef float f32x4 __attribute__((ext_vector_type(4)));

// non-temporal float4 load via native vector type (builtin rejects HIP_vector_type)
__device__ inline f32x4 ntload4(const float* p) {
    return __builtin_nontemporal_load(reinterpret_cast<const f32x4*>(p));
}

// ---------- prep: frag-major f16 hi/lo split + e2 (LDS reduce) + sum(cluster_size) ----
__global__ __launch_bounds__(512) void prep_kernel(
    const float* __restrict__ emb, const float* __restrict__ cluster_size,
    f16* __restrict__ eh2, f16* __restrict__ el2, float* __restrict__ e2,
    float* __restrict__ cs_sum, int K)
{
    __shared__ float red[512];
    int t = blockIdx.x * 512 + threadIdx.x;
    int lane = t & 63;
    int sub  = (t >> 6) & 7;
    int tile = t >> 9;
    int wn = sub >> 2, nf = (sub >> 1) & 1, ks = sub & 1;
    int lrow = lane & 15, lkg = lane >> 4;
    int k  = tile * 64 + wn * 32 + nf * 16 + lrow;
    int d0 = ks * 32 + lkg * 8;

    const float4* p = reinterpret_cast<const float4*>(emb + (size_t)k * D + d0);
    float4 a = p[0], b = p[1];
    float v[8] = {a.x, a.y, a.z, a.w, b.x, b.y, b.z, b.w};
    union { f16 h[8]; uint4 u; } H, L;
    float part = 0.f;
#pragma unroll
    for (int j = 0; j < 8; ++j) {
        part = fmaf(v[j], v[j], part);
        f16 h = (f16)v[j];
        H.h[j] = h;
        L.h[j] = (f16)((v[j] - (float)h) * 2048.0f);
    }
    reinterpret_cast<uint4*>(eh2)[t] = H.u;
    reinterpret_cast<uint4*>(el2)[t] = L.u;

    red[threadIdx.x] = part;

    if (blockIdx.x < (K >> 9)) {
        float cv = cluster_size[t];
#pragma unroll
        for (int m = 1; m < 64; m <<= 1) cv += __shfl_xor(cv, m, 64);
        if ((threadIdx.x & 63) == 0) atomicAdd(cs_sum, cv);
    }
    __syncthreads();

    if (threadIdx.x < 64) {
        int r = threadIdx.x;
        int rwn = r >> 5, rnf = (r >> 4) & 1, rlr = r & 15;
        float s = 0.f;
#pragma unroll
        for (int kks = 0; kks < 2; ++kks)
#pragma unroll
            for (int g = 0; g < 4; ++g)
                s += red[((rwn * 2 + rnf) * 2 + kks) * 64 + g * 16 + rlr];
        e2[tile * 64 + r] = s;
    }
}

// ---------- MFMA 3-pass split-f16 (round-13 structure) + nt x-loads ----------
__global__ __launch_bounds__(256, 2) void argmin_kernel(
    const float* __restrict__ x, const f16* __restrict__ eh2, const f16* __restrict__ el2,
    const float* __restrict__ e2, int* __restrict__ pidx, int n, int K)
{
    __shared__ float se2a[1024];     // whole-chunk +0.5*e2 (4KB)

    const int tx   = threadIdx.x;
    const int lane = tx & 63;
    const int wid  = tx >> 6;
    const int wm   = wid >> 1, wn = wid & 1;
    const int lrow = lane & 15;
    const int lkg  = lane >> 4;

    const int chunk = blockIdx.x % NCHUNK;
    const int mblk  = blockIdx.x / NCHUNK;
    const int q0    = mblk * BM;
    const int kc    = K / NCHUNK;    // 1024
    const int k0    = chunk * kc;
    const int gt0   = chunk * (kc / 64);
    const int NT    = kc / 64;       // 16 tiles of 64 codes

    // ---- A fragments (NEGATED, non-temporal x): f16 hi/lo + 0.5*f2 per slot ----
    f16x8 ah[4][2], al[4][2];
    f32x4 hf2[4];
#pragma unroll
    for (int m = 0; m < 4; ++m) {
        float f2part = 0.f;
#pragma unroll
        for (int ks = 0; ks < 2; ++ks) {
            int row = q0 + wm * 64 + m * 16 + lrow;
            const float* p = x + (size_t)row * D + ks * 32 + lkg * 8;
            f32x4 va = ntload4(p), vb = ntload4(p + 4);   // nt: don't evict B-stream
            float t[8] = {va[0], va[1], va[2], va[3], vb[0], vb[1], vb[2], vb[3]};
#pragma unroll
            for (int j = 0; j < 8; ++j) {
                f2part = fmaf(t[j], t[j], f2part);
                float nt = -t[j];
                f16 h = (f16)nt;
                ah[m][ks][j] = h;
                al[m][ks][j] = (f16)((nt - (float)h) * 2048.0f);
            }
        }
        f2part += __shfl_xor(f2part, 16, 64);
        f2part += __shfl_xor(f2part, 32, 64);
#pragma unroll
        for (int r = 0; r < 4; ++r)
            hf2[m][r] = 0.5f * __shfl(f2part, lkg * 4 + r, 64);
    }

    // ---- whole-chunk e2 table, prescaled by +0.5 ----
    for (int i = tx; i < kc; i += 256) se2a[i] = 0.5f * e2[k0 + i];
    __syncthreads();   // the ONLY barrier

    // ---- packed top-1 (MINIMIZE uint(t')|tag) per C-slot ----
    unsigned int pbest[16];
#pragma unroll
    for (int s = 0; s < 16; ++s) pbest[s] = 0xFFFFFFFFu;

    auto LOADB = [&](f16x8 (&BH)[2][2], f16x8 (&BL)[2][2], int ttv) {
        const f16* bhb = eh2 + ((size_t)(gt0 + ttv) << 12);
        const f16* blb = el2 + ((size_t)(gt0 + ttv) << 12);
#pragma unroll
        for (int nf = 0; nf < 2; ++nf)
#pragma unroll
            for (int ks = 0; ks < 2; ++ks) {
                int sub = (wn * 2 + nf) * 2 + ks;
                BH[nf][ks] = *reinterpret_cast<const f16x8*>(bhb + sub * 512 + lane * 8);
                BL[nf][ks] = *reinterpret_cast<const f16x8*>(blb + sub * 512 + lane * 8);
            }
    };

    auto COMPUTE = [&](const f16x8 (&BH)[2][2], const f16x8 (&BL)[2][2], int ttv) {
        const float he0 = se2a[ttv * 64 + wn * 32 + lrow];
        const float he1 = se2a[ttv * 64 + wn * 32 + 16 + lrow];
        const unsigned int tagA = (unsigned int)(ttv * 2);
        const unsigned int tagB = tagA + 1u;
#pragma unroll
        for (int m = 0; m < 4; ++m) {
            f32x4 hh0 = hf2[m] + he0;
            f32x4 hh1 = hf2[m] + he1;
            f32x4 md0 = {0.f, 0.f, 0.f, 0.f};
            f32x4 md1 = {0.f, 0.f, 0.f, 0.f};
            __builtin_amdgcn_s_setprio(1);
            hh0 = __builtin_amdgcn_mfma_f32_16x16x32_f16(ah[m][0], BH[0][0], hh0, 0, 0, 0);
            hh1 = __builtin_amdgcn_mfma_f32_16x16x32_f16(ah[m][0], BH[1][0], hh1, 0, 0, 0);
            hh0 = __builtin_amdgcn_mfma_f32_16x16x32_f16(ah[m][1], BH[0][1], hh0, 0, 0, 0);
            hh1 = __builtin_amdgcn_mfma_f32_16x16x32_f16(ah[m][1], BH[1][1], hh1, 0, 0, 0);
            md0 = __builtin_amdgcn_mfma_f32_16x16x32_f16(al[m][0], BH[0][0], md0, 0, 0, 0);
            md1 = __builtin_amdgcn_mfma_f32_16x16x32_f16(al[m][0], BH[1][0], md1, 0, 0, 0);
            md0 = __builtin_amdgcn_mfma_f32_16x16x32_f16(al[m][1], BH[0][1], md0, 0, 0, 0);
            md1 = __builtin_amdgcn_mfma_f32_16x16x32_f16(al[m][1], BH[1][1], md1, 0, 0, 0);
            md0 = __builtin_amdgcn_mfma_f32_16x16x32_f16(ah[m][0], BL[0][0], md0, 0, 0, 0);
            md1 = __builtin_amdgcn_mfma_f32_16x16x32_f16(ah[m][0], BL[1][0], md1, 0, 0, 0);
            md0 = __builtin_amdgcn_mfma_f32_16x16x32_f16(ah[m][1], BL[0][1], md0, 0, 0, 0);
            md1 = __builtin_amdgcn_mfma_f32_16x16x32_f16(ah[m][1], BL[1][1], md1, 0, 0, 0);
            __builtin_amdgcn_s_setprio(0);
#pragma unroll
            for (int r = 0; r < 4; ++r) {
                float tA = fmaf(md0[r], INVS, hh0[r]);   // 0.5*d2, >= 0
                float tB = fmaf(md1[r], INVS, hh1[r]);
                unsigned int uA = (__float_as_uint(tA) & 0xFFFFFFE0u) | tagA;
                unsigned int uB = (__float_as_uint(tB) & 0xFFFFFFE0u) | tagB;
                unsigned int w = uA < uB ? uA : uB;
                int s = m * 4 + r;
                pbest[s] = pbest[s] < w ? pbest[s] : w;
            }
        }
    };

    // ---- 2-stage register pipeline: load(t+1) overlaps compute(t) ----
    f16x8 bh[2][2], bl[2][2], nh[2][2], nl[2][2];
    LOADB(bh, bl, 0);
#pragma unroll 1
    for (int tt = 0; tt < NT; tt += 2) {
        LOADB(nh, nl, tt + 1);           // NT even: tt+1 < NT always
        COMPUTE(bh, bl, tt);
        if (tt + 2 < NT) LOADB(bh, bl, tt + 2);
        COMPUTE(nh, nl, tt + 1);
    }

    // ---- merge across the 16 col-lanes (min packed; tie -> lower code id) ----
#pragma unroll
    for (int s = 0; s < 16; ++s) {
        unsigned int u = pbest[s];
        unsigned int tag = u & 31u;
        int cid = (int)((tag >> 1) << 6) | (int)((tag & 1u) << 4) | (wn << 5) | lrow;
#pragma unroll
        for (int xm = 1; xm < 16; xm <<= 1) {
            unsigned int ou = __shfl_xor(u, xm, 64);
            int          oc = __shfl_xor(cid, xm, 64);
            if (ou < u || (ou == u && oc < cid)) { u = ou; cid = oc; }
        }
        if (lrow == 0) {
            int m = s >> 2, r = s & 3;
            int row = q0 + wm * 64 + m * 16 + lkg * 4 + r;
            pidx[(size_t)(chunk * 2 + wn) * n + row] = k0 + cid;
        }
    }
}

// ---------- fused exact re-rank + quantize + scatter: wave/query, 4 lanes/candidate ----
__global__ __launch_bounds__(256) void rerank_kernel(
    const float* __restrict__ x, const float* __restrict__ emb, const float* __restrict__ e2,
    const int* __restrict__ pidx, float* __restrict__ out_ind, float* __restrict__ quant,
    float* __restrict__ embed_sum, float* __restrict__ counts, int n)
{
    int gid  = blockIdx.x * blockDim.x + threadIdx.x;
    int q    = gid >> 6;
    int lane = gid & 63;
    int c    = lane >> 2;
    int j    = lane & 3;
    if (q >= n) return;

    int k = pidx[(size_t)c * n + q];
    const float4* ep = reinterpret_cast<const float4*>(emb + (size_t)k * D);
    const float4* xp = reinterpret_cast<const float4*>(x + (size_t)q * D);

    float a0 = 0.f, a1 = 0.f, a2 = 0.f, a3 = 0.f;
#pragma unroll
    for (int i = 0; i < 4; ++i) {
        float4 e4 = ep[j + 4 * i];
        float4 x4 = xp[j + 4 * i];
        a0 = fmaf(x4.x, e4.x, a0);
        a1 = fmaf(x4.y, e4.y, a1);
        a2 = fmaf(x4.z, e4.z, a2);
        a3 = fmaf(x4.w, e4.w, a3);
    }
    float p = (a0 + a1) + (a2 + a3);
    p += __shfl_xor(p, 1, 64);
    p += __shfl_xor(p, 2, 64);
    float dist = fmaf(p, -2.0f, e2[k]);
    int   bk   = k;

#pragma unroll
    for (int xm = 4; xm < 64; xm <<= 1) {
        float od = __shfl_xor(dist, xm, 64);
        int   ok = __shfl_xor(bk, xm, 64);
        if (od < dist || (od == dist && ok < bk)) { dist = od; bk = ok; }
    }

    float xv = x[(size_t)q * D + lane];
    quant[(size_t)q * D + lane] = emb[(size_t)bk * D + lane];
    atomicAdd(embed_sum + (size_t)bk * D + lane, xv);
    if (lane == 0) {
        out_ind[q] = (float)bk;
        atomicAdd(counts + bk, 1.0f);
    }
}

// ---------- single fused EMA: cluster_size + embed_avg + normalize ----------
__global__ __launch_bounds__(256) void ema_kernel(
    const float* __restrict__ cluster_size, const float* __restrict__ embed_avg,
    const float* __restrict__ cs_sum, float* __restrict__ ncs,
    float* __restrict__ nea, float* __restrict__ enorm, int K, int n)
{
    int gid = blockIdx.x * blockDim.x + threadIdx.x;
    if (gid >= K * D) return;
    int k = gid >> 6;
    float total = DECAYF * cs_sum[0] + OMDF * (float)n;
    float cnew  = cluster_size[k] * DECAYF + ncs[k] * OMDF;
    if ((gid & 63) == 0) ncs[k] = cnew;
    float v = embed_avg[gid] * DECAYF + nea[gid] * OMDF;
    nea[gid] = v;
    float smoothed = (cnew + EPSF) / (total + (float)K * EPSF) * total;
    enorm[gid] = v / smoothed;
}

extern "C" void kernel_launch(void* const* d_in, const int* in_sizes, int n_in,
                              void* d_out, int out_size, void* d_ws, size_t ws_size,
                              hipStream_t stream) {
    const float* x            = (const float*)d_in[0];   // [n, 64]
    const float* emb          = (const float*)d_in[1];   // [K, 64]
    const float* cluster_size = (const float*)d_in[2];   // [K]
    const float* embed_avg    = (const float*)d_in[3];   // [K, 64]

    const int n = in_sizes[0] / D;   // 16384
    const int K = in_sizes[1] / D;   // 8192

    // output layout (fp32): quantize | embed_ind | embed_normalized | new_cluster_size | new_embed_avg
    float* out     = (float*)d_out;
    float* quant   = out;                        // n*D
    float* out_ind = quant + (size_t)n * D;      // n
    float* enorm   = out_ind + n;                // K*D  (scratch for eh2/el2 until ema)
    float* ncs     = enorm + (size_t)K * D;      // K    (counts, then EMA'd in place)
    float* nea     = ncs + K;                    // K*D  (embed_sum, then EMA'd in place)

    f16* eh2 = reinterpret_cast<f16*>(enorm);    // K*D f16, fragment-major
    f16* el2 = eh2 + (size_t)K * D;              // K*D f16, fragment-major

    // workspace: e2 | pidx[NLIST][n] | cs_sum
    float* e2     = (float*)d_ws;                        // K
    int*   pidx   = (int*)(e2 + K);                      // NLIST*n
    float* cs_sum = (float*)(pidx + (size_t)NLIST * n);  // 1

    hipMemsetAsync(ncs, 0, (size_t)K * sizeof(float), stream);
    hipMemsetAsync(nea, 0, (size_t)K * D * sizeof(float), stream);
    hipMemsetAsync(cs_sum, 0, sizeof(float), stream);

    prep_kernel<<<K * 8 / 512, 512, 0, stream>>>(emb, cluster_size, eh2, el2, e2, cs_sum, K);
    argmin_kernel<<<(n / BM) * NCHUNK, 256, 0, stream>>>(x, eh2, el2, e2, pidx, n, K);
    rerank_kernel<<<(n * 64 + 255) / 256, 256, 0, stream>>>(
        x, emb, e2, pidx, out_ind, quant, nea, ncs, n);
    ema_kernel<<<(K * D + 255) / 256, 256, 0, stream>>>(
        cluster_size, embed_avg, cs_sum, ncs, nea, enorm, K, n);
}

// Round 17
// 88.870 us; speedup vs baseline: 2.5816x; 1.0942x over previous
//
#include <hip/hip_runtime.h>

#define D 64
#define BM 128        // queries per block
#define NCHUNK 8      // K split across blocks
#define NLIST (2 * NCHUNK)   // one winner list per (chunk, wn-wave)
#define DECAYF 0.8f
#define OMDF 0.2f
#define EPSF 1e-5f
#define INVS 4.8828125e-4f   // 2^-11

typedef _Float16 f16;
typedef _Float16 f16x8 __attribute__((ext_vector_type(8)));
typedef float f32x4 __attribute__((ext_vector_type(4)));

// ---------- prep: frag-major f16 hi/lo split + e2 (LDS reduce) + sum(cluster_size)
//            + zero-init of the ncs/nea accumulation targets (replaces 2 memsets) ----
__global__ __launch_bounds__(512) void prep_kernel(
    const float* __restrict__ emb, const float* __restrict__ cluster_size,
    f16* __restrict__ eh2, f16* __restrict__ el2, float* __restrict__ e2,
    float* __restrict__ cs_sum, float* __restrict__ ncs, float* __restrict__ nea,
    int K)
{
    __shared__ float red[512];
    int t = blockIdx.x * 512 + threadIdx.x;
    int lane = t & 63;
    int sub  = (t >> 6) & 7;
    int tile = t >> 9;
    int wn = sub >> 2, nf = (sub >> 1) & 1, ks = sub & 1;
    int lrow = lane & 15, lkg = lane >> 4;
    int k  = tile * 64 + wn * 32 + nf * 16 + lrow;
    int d0 = ks * 32 + lkg * 8;

    // zero accumulation targets (runs before argmin/rerank in stream order)
    {
        float4 z = {0.f, 0.f, 0.f, 0.f};
        float4* nea4 = reinterpret_cast<float4*>(nea);
        nea4[t]         = z;                 // K*D/4 = 131072 float4, 65536 threads x2
        nea4[t + 65536] = z;
        if (t < 2048) reinterpret_cast<float4*>(ncs)[t] = z;   // K/4 = 2048
    }

    const float4* p = reinterpret_cast<const float4*>(emb + (size_t)k * D + d0);
    float4 a = p[0], b = p[1];
    float v[8] = {a.x, a.y, a.z, a.w, b.x, b.y, b.z, b.w};
    union { f16 h[8]; uint4 u; } H, L;
    float part = 0.f;
#pragma unroll
    for (int j = 0; j < 8; ++j) {
        part = fmaf(v[j], v[j], part);
        f16 h = (f16)v[j];
        H.h[j] = h;
        L.h[j] = (f16)((v[j] - (float)h) * 2048.0f);
    }
    reinterpret_cast<uint4*>(eh2)[t] = H.u;
    reinterpret_cast<uint4*>(el2)[t] = L.u;

    red[threadIdx.x] = part;

    if (blockIdx.x < (K >> 9)) {
        float cv = cluster_size[t];
#pragma unroll
        for (int m = 1; m < 64; m <<= 1) cv += __shfl_xor(cv, m, 64);
        if ((threadIdx.x & 63) == 0) atomicAdd(cs_sum, cv);
    }
    __syncthreads();

    if (threadIdx.x < 64) {
        int r = threadIdx.x;
        int rwn = r >> 5, rnf = (r >> 4) & 1, rlr = r & 15;
        float s = 0.f;
#pragma unroll
        for (int kks = 0; kks < 2; ++kks)
#pragma unroll
            for (int g = 0; g < 4; ++g)
                s += red[((rwn * 2 + rnf) * 2 + kks) * 64 + g * 16 + rlr];
        e2[tile * 64 + r] = s;
    }
}

// ---------- MFMA 3-pass split-f16 (round-13 structure, best measured: 70us) ----------
__global__ __launch_bounds__(256, 2) void argmin_kernel(
    const float* __restrict__ x, const f16* __restrict__ eh2, const f16* __restrict__ el2,
    const float* __restrict__ e2, int* __restrict__ pidx, int n, int K)
{
    __shared__ float se2a[1024];     // whole-chunk +0.5*e2 (4KB)

    const int tx   = threadIdx.x;
    const int lane = tx & 63;
    const int wid  = tx >> 6;
    const int wm   = wid >> 1, wn = wid & 1;
    const int lrow = lane & 15;
    const int lkg  = lane >> 4;

    const int chunk = blockIdx.x % NCHUNK;
    const int mblk  = blockIdx.x / NCHUNK;
    const int q0    = mblk * BM;
    const int kc    = K / NCHUNK;    // 1024
    const int k0    = chunk * kc;
    const int gt0   = chunk * (kc / 64);
    const int NT    = kc / 64;       // 16 tiles of 64 codes

    // ---- A fragments (NEGATED): fp32 x rows -> f16 hi/lo; also 0.5*f2 per slot ----
    f16x8 ah[4][2], al[4][2];
    f32x4 hf2[4];
#pragma unroll
    for (int m = 0; m < 4; ++m) {
        float f2part = 0.f;
#pragma unroll
        for (int ks = 0; ks < 2; ++ks) {
            int row = q0 + wm * 64 + m * 16 + lrow;
            const float4* p = reinterpret_cast<const float4*>(
                x + (size_t)row * D + ks * 32 + lkg * 8);
            float4 va = p[0], vb = p[1];
            float t[8] = {va.x, va.y, va.z, va.w, vb.x, vb.y, vb.z, vb.w};
#pragma unroll
            for (int j = 0; j < 8; ++j) {
                f2part = fmaf(t[j], t[j], f2part);
                float nt = -t[j];
                f16 h = (f16)nt;
                ah[m][ks][j] = h;
                al[m][ks][j] = (f16)((nt - (float)h) * 2048.0f);
            }
        }
        f2part += __shfl_xor(f2part, 16, 64);
        f2part += __shfl_xor(f2part, 32, 64);
#pragma unroll
        for (int r = 0; r < 4; ++r)
            hf2[m][r] = 0.5f * __shfl(f2part, lkg * 4 + r, 64);
    }

    // ---- whole-chunk e2 table, prescaled by +0.5 ----
    for (int i = tx; i < kc; i += 256) se2a[i] = 0.5f * e2[k0 + i];
    __syncthreads();   // the ONLY barrier

    // ---- packed top-1 (MINIMIZE uint(t')|tag) per C-slot ----
    unsigned int pbest[16];
#pragma unroll
    for (int s = 0; s < 16; ++s) pbest[s] = 0xFFFFFFFFu;

    auto LOADB = [&](f16x8 (&BH)[2][2], f16x8 (&BL)[2][2], int ttv) {
        const f16* bhb = eh2 + ((size_t)(gt0 + ttv) << 12);
        const f16* blb = el2 + ((size_t)(gt0 + ttv) << 12);
#pragma unroll
        for (int nf = 0; nf < 2; ++nf)
#pragma unroll
            for (int ks = 0; ks < 2; ++ks) {
                int sub = (wn * 2 + nf) * 2 + ks;
                BH[nf][ks] = *reinterpret_cast<const f16x8*>(bhb + sub * 512 + lane * 8);
                BL[nf][ks] = *reinterpret_cast<const f16x8*>(blb + sub * 512 + lane * 8);
            }
    };

    auto COMPUTE = [&](const f16x8 (&BH)[2][2], const f16x8 (&BL)[2][2], int ttv) {
        const float he0 = se2a[ttv * 64 + wn * 32 + lrow];
        const float he1 = se2a[ttv * 64 + wn * 32 + 16 + lrow];
        const unsigned int tagA = (unsigned int)(ttv * 2);
        const unsigned int tagB = tagA + 1u;
#pragma unroll
        for (int m = 0; m < 4; ++m) {
            f32x4 hh0 = hf2[m] + he0;
            f32x4 hh1 = hf2[m] + he1;
            f32x4 md0 = {0.f, 0.f, 0.f, 0.f};
            f32x4 md1 = {0.f, 0.f, 0.f, 0.f};
            __builtin_amdgcn_s_setprio(1);
            hh0 = __builtin_amdgcn_mfma_f32_16x16x32_f16(ah[m][0], BH[0][0], hh0, 0, 0, 0);
            hh1 = __builtin_amdgcn_mfma_f32_16x16x32_f16(ah[m][0], BH[1][0], hh1, 0, 0, 0);
            hh0 = __builtin_amdgcn_mfma_f32_16x16x32_f16(ah[m][1], BH[0][1], hh0, 0, 0, 0);
            hh1 = __builtin_amdgcn_mfma_f32_16x16x32_f16(ah[m][1], BH[1][1], hh1, 0, 0, 0);
            md0 = __builtin_amdgcn_mfma_f32_16x16x32_f16(al[m][0], BH[0][0], md0, 0, 0, 0);
            md1 = __builtin_amdgcn_mfma_f32_16x16x32_f16(al[m][0], BH[1][0], md1, 0, 0, 0);
            md0 = __builtin_amdgcn_mfma_f32_16x16x32_f16(al[m][1], BH[0][1], md0, 0, 0, 0);
            md1 = __builtin_amdgcn_mfma_f32_16x16x32_f16(al[m][1], BH[1][1], md1, 0, 0, 0);
            md0 = __builtin_amdgcn_mfma_f32_16x16x32_f16(ah[m][0], BL[0][0], md0, 0, 0, 0);
            md1 = __builtin_amdgcn_mfma_f32_16x16x32_f16(ah[m][0], BL[1][0], md1, 0, 0, 0);
            md0 = __builtin_amdgcn_mfma_f32_16x16x32_f16(ah[m][1], BL[0][1], md0, 0, 0, 0);
            md1 = __builtin_amdgcn_mfma_f32_16x16x32_f16(ah[m][1], BL[1][1], md1, 0, 0, 0);
            __builtin_amdgcn_s_setprio(0);
#pragma unroll
            for (int r = 0; r < 4; ++r) {
                float tA = fmaf(md0[r], INVS, hh0[r]);   // 0.5*d2, >= 0
                float tB = fmaf(md1[r], INVS, hh1[r]);
                unsigned int uA = (__float_as_uint(tA) & 0xFFFFFFE0u) | tagA;
                unsigned int uB = (__float_as_uint(tB) & 0xFFFFFFE0u) | tagB;
                unsigned int w = uA < uB ? uA : uB;
                int s = m * 4 + r;
                pbest[s] = pbest[s] < w ? pbest[s] : w;
            }
        }
    };

    // ---- 2-stage register pipeline: load(t+1) overlaps compute(t) ----
    f16x8 bh[2][2], bl[2][2], nh[2][2], nl[2][2];
    LOADB(bh, bl, 0);
#pragma unroll 1
    for (int tt = 0; tt < NT; tt += 2) {
        LOADB(nh, nl, tt + 1);           // NT even: tt+1 < NT always
        COMPUTE(bh, bl, tt);
        if (tt + 2 < NT) LOADB(bh, bl, tt + 2);
        COMPUTE(nh, nl, tt + 1);
    }

    // ---- merge across the 16 col-lanes (min packed; tie -> lower code id) ----
#pragma unroll
    for (int s = 0; s < 16; ++s) {
        unsigned int u = pbest[s];
        unsigned int tag = u & 31u;
        int cid = (int)((tag >> 1) << 6) | (int)((tag & 1u) << 4) | (wn << 5) | lrow;
#pragma unroll
        for (int xm = 1; xm < 16; xm <<= 1) {
            unsigned int ou = __shfl_xor(u, xm, 64);
            int          oc = __shfl_xor(cid, xm, 64);
            if (ou < u || (ou == u && oc < cid)) { u = ou; cid = oc; }
        }
        if (lrow == 0) {
            int m = s >> 2, r = s & 3;
            int row = q0 + wm * 64 + m * 16 + lkg * 4 + r;
            pidx[(size_t)(chunk * 2 + wn) * n + row] = k0 + cid;
        }
    }
}

// ---------- fused exact re-rank + quantize + scatter: wave/query, 4 lanes/candidate ----
__global__ __launch_bounds__(256) void rerank_kernel(
    const float* __restrict__ x, const float* __restrict__ emb, const float* __restrict__ e2,
    const int* __restrict__ pidx, float* __restrict__ out_ind, float* __restrict__ quant,
    float* __restrict__ embed_sum, float* __restrict__ counts, int n)
{
    int gid  = blockIdx.x * blockDim.x + threadIdx.x;
    int q    = gid >> 6;
    int lane = gid & 63;
    int c    = lane >> 2;
    int j    = lane & 3;
    if (q >= n) return;

    int k = pidx[(size_t)c * n + q];
    const float4* ep = reinterpret_cast<const float4*>(emb + (size_t)k * D);
    const float4* xp = reinterpret_cast<const float4*>(x + (size_t)q * D);

    float a0 = 0.f, a1 = 0.f, a2 = 0.f, a3 = 0.f;
#pragma unroll
    for (int i = 0; i < 4; ++i) {
        float4 e4 = ep[j + 4 * i];
        float4 x4 = xp[j + 4 * i];
        a0 = fmaf(x4.x, e4.x, a0);
        a1 = fmaf(x4.y, e4.y, a1);
        a2 = fmaf(x4.z, e4.z, a2);
        a3 = fmaf(x4.w, e4.w, a3);
    }
    float p = (a0 + a1) + (a2 + a3);
    p += __shfl_xor(p, 1, 64);
    p += __shfl_xor(p, 2, 64);
    float dist = fmaf(p, -2.0f, e2[k]);
    int   bk   = k;

#pragma unroll
    for (int xm = 4; xm < 64; xm <<= 1) {
        float od = __shfl_xor(dist, xm, 64);
        int   ok = __shfl_xor(bk, xm, 64);
        if (od < dist || (od == dist && ok < bk)) { dist = od; bk = ok; }
    }

    float xv = x[(size_t)q * D + lane];
    quant[(size_t)q * D + lane] = emb[(size_t)bk * D + lane];
    atomicAdd(embed_sum + (size_t)bk * D + lane, xv);
    if (lane == 0) {
        out_ind[q] = (float)bk;
        atomicAdd(counts + bk, 1.0f);
    }
}

// ---------- single fused EMA: cluster_size + embed_avg + normalize ----------
__global__ __launch_bounds__(256) void ema_kernel(
    const float* __restrict__ cluster_size, const float* __restrict__ embed_avg,
    const float* __restrict__ cs_sum, float* __restrict__ ncs,
    float* __restrict__ nea, float* __restrict__ enorm, int K, int n)
{
    int gid = blockIdx.x * blockDim.x + threadIdx.x;
    if (gid >= K * D) return;
    int k = gid >> 6;
    float total = DECAYF * cs_sum[0] + OMDF * (float)n;
    float cnew  = cluster_size[k] * DECAYF + ncs[k] * OMDF;
    if ((gid & 63) == 0) ncs[k] = cnew;
    float v = embed_avg[gid] * DECAYF + nea[gid] * OMDF;
    nea[gid] = v;
    float smoothed = (cnew + EPSF) / (total + (float)K * EPSF) * total;
    enorm[gid] = v / smoothed;
}

extern "C" void kernel_launch(void* const* d_in, const int* in_sizes, int n_in,
                              void* d_out, int out_size, void* d_ws, size_t ws_size,
                              hipStream_t stream) {
    const float* x            = (const float*)d_in[0];   // [n, 64]
    const float* emb          = (const float*)d_in[1];   // [K, 64]
    const float* cluster_size = (const float*)d_in[2];   // [K]
    const float* embed_avg    = (const float*)d_in[3];   // [K, 64]

    const int n = in_sizes[0] / D;   // 16384
    const int K = in_sizes[1] / D;   // 8192

    // output layout (fp32): quantize | embed_ind | embed_normalized | new_cluster_size | new_embed_avg
    float* out     = (float*)d_out;
    float* quant   = out;                        // n*D
    float* out_ind = quant + (size_t)n * D;      // n
    float* enorm   = out_ind + n;                // K*D  (scratch for eh2/el2 until ema)
    float* ncs     = enorm + (size_t)K * D;      // K    (counts, then EMA'd in place)
    float* nea     = ncs + K;                    // K*D  (embed_sum, then EMA'd in place)

    f16* eh2 = reinterpret_cast<f16*>(enorm);    // K*D f16, fragment-major
    f16* el2 = eh2 + (size_t)K * D;              // K*D f16, fragment-major

    // workspace: e2 | pidx[NLIST][n] | cs_sum
    float* e2     = (float*)d_ws;                        // K
    int*   pidx   = (int*)(e2 + K);                      // NLIST*n
    float* cs_sum = (float*)(pidx + (size_t)NLIST * n);  // 1

    // only cs_sum needs a memset (prep atomics into it); ncs/nea zeroed inside prep
    hipMemsetAsync(cs_sum, 0, sizeof(float), stream);

    prep_kernel<<<K * 8 / 512, 512, 0, stream>>>(
        emb, cluster_size, eh2, el2, e2, cs_sum, ncs, nea, K);
    argmin_kernel<<<(n / BM) * NCHUNK, 256, 0, stream>>>(x, eh2, el2, e2, pidx, n, K);
    rerank_kernel<<<(n * 64 + 255) / 256, 256, 0, stream>>>(
        x, emb, e2, pidx, out_ind, quant, nea, ncs, n);
    ema_kernel<<<(K * D + 255) / 256, 256, 0, stream>>>(
        cluster_size, embed_avg, cs_sum, ncs, nea, enorm, K, n);
}